// Round 8
// baseline (34.744 us; speedup 1.0000x reference)
//
#include <hip/hip_runtime.h>
#include <math.h>

// CropPoolLayer: TF crop_and_resize (bilinear, extrapolation=0) to 14x14
// fused with 2x2 max pool -> [N,7,7,C], NHWC fp32.
// bottom [B=2,H=64,W=64,C=512] fp32, rois [N,5] (bid,x1,y1,x2,y2), im_info[2].
//
// R8: two-kernel split. Kernel 1 (tiny, 98 blocks) precomputes per-cell
// geometry (8 premultiplied corner indices, 4 lerp weights, validity mask)
// into d_ws (25088 x 64B). Kernel 2 (the hot one) reads its 64B geometry
// uniformly (readfirstlane -> SGPRs), issues corner loads with uniform-branch
// dedup immediately, lerps, nt-stores. Removes the ~500-cycle serial
// geometry chain from every one of the 50k hot waves (chain-stall theory).

constexpr int POOLSZ = 7;
constexpr int CROPSZ = 14;
constexpr int Hc = 64, Wc = 64, C4 = 128;     // C=512 -> 128 float4 lanes
constexpr int NCELLS_WORDS = 16;              // 64 B per cell

typedef float vfloat4 __attribute__((ext_vector_type(4)));

__device__ __forceinline__ float4 lerp4(float4 a, float4 b, float t) {
    return make_float4(fmaf(b.x - a.x, t, a.x),
                       fmaf(b.y - a.y, t, a.y),
                       fmaf(b.z - a.z, t, a.z),
                       fmaf(b.w - a.w, t, a.w));
}
__device__ __forceinline__ float4 f4max(float4 a, float4 b) {
    return make_float4(fmaxf(a.x, b.x), fmaxf(a.y, b.y),
                       fmaxf(a.z, b.z), fmaxf(a.w, b.w));
}
__device__ __forceinline__ float4 mask4(float4 v, bool ok) {
    return ok ? v : make_float4(0.f, 0.f, 0.f, 0.f);
}
__device__ __forceinline__ int rfl(int x) { return __builtin_amdgcn_readfirstlane(x); }

// ---------------- kernel 1: per-cell geometry precompute ----------------
__global__ __launch_bounds__(256)
void geom_kernel(const float* __restrict__ rois,
                 const float* __restrict__ im_info,
                 int* __restrict__ gout, int ncells)
{
    const int cell = blockIdx.x * 256 + threadIdx.x;
    if (cell >= ncells) return;
    const int n  = cell / (POOLSZ * POOLSZ);
    const int p  = cell - n * (POOLSZ * POOLSZ);
    const int py = p / POOLSZ;
    const int px = p - py * POOLSZ;

    const float inv_w = 1.0f / im_info[1];     // im=1024 (pow2) -> exact
    const float inv_h = 1.0f / im_info[0];
    const float* r5 = rois + n * 5;
    const int bb = (int)r5[0];
    const float rx1 = r5[1] * inv_w, ry1 = r5[2] * inv_h;
    const float rx2 = r5[3] * inv_w, ry2 = r5[4] * inv_h;

    const float sy = (ry2 - ry1) * (float)(Hc - 1) / (float)(CROPSZ - 1);
    const float sx = (rx2 - rx1) * (float)(Wc - 1) / (float)(CROPSZ - 1);
    const float oy = ry1 * (float)(Hc - 1);
    const float ox = rx1 * (float)(Wc - 1);

    int g[NCELLS_WORDS];
    // y slots
    const float ysa = fmaf((float)(2 * py), sy, oy);
    const bool vy0 = (ysa >= 0.f) && (ysa <= (float)(Hc - 1));
    const float fy = floorf(ysa); const float ly0 = ysa - fy;      // unclipped
    const int y0 = (int)fminf(fmaxf(fy, 0.f), (float)(Hc - 1));
    const int y1 = (int)fminf(fmaxf(ceilf(ysa), 0.f), (float)(Hc - 1));
    g[0] = ((bb * Hc + y0) * Wc) * C4;
    g[1] = ((bb * Hc + y1) * Wc) * C4;
    const float ysb = fmaf((float)(2 * py + 1), sy, oy);
    const bool vy1 = (ysb >= 0.f) && (ysb <= (float)(Hc - 1));
    const float fy2 = floorf(ysb); const float ly1 = ysb - fy2;
    const int y2 = (int)fminf(fmaxf(fy2, 0.f), (float)(Hc - 1));
    const int y3 = (int)fminf(fmaxf(ceilf(ysb), 0.f), (float)(Hc - 1));
    g[2] = ((bb * Hc + y2) * Wc) * C4;
    g[3] = ((bb * Hc + y3) * Wc) * C4;
    // x slots
    const float xsa = fmaf((float)(2 * px), sx, ox);
    const bool vx0 = (xsa >= 0.f) && (xsa <= (float)(Wc - 1));
    const float fx = floorf(xsa); const float lx0 = xsa - fx;      // unclipped
    g[4] = (int)fminf(fmaxf(fx, 0.f), (float)(Wc - 1)) * C4;
    g[5] = (int)fminf(fmaxf(ceilf(xsa), 0.f), (float)(Wc - 1)) * C4;
    const float xsb = fmaf((float)(2 * px + 1), sx, ox);
    const bool vx1 = (xsb >= 0.f) && (xsb <= (float)(Wc - 1));
    const float fx2 = floorf(xsb); const float lx1 = xsb - fx2;
    g[6] = (int)fminf(fmaxf(fx2, 0.f), (float)(Wc - 1)) * C4;
    g[7] = (int)fminf(fmaxf(ceilf(xsb), 0.f), (float)(Wc - 1)) * C4;
    // weights + mask
    g[8]  = __float_as_int(lx0);
    g[9]  = __float_as_int(lx1);
    g[10] = __float_as_int(ly0);
    g[11] = __float_as_int(ly1);
    g[12] = (int)((vy0 && vx0) ? 1u : 0u) | ((vy0 && vx1) ? 2u : 0u)
          | ((vy1 && vx0) ? 4u : 0u) | ((vy1 && vx1) ? 8u : 0u);
    g[13] = g[14] = g[15] = 0;

    int4* dst = reinterpret_cast<int4*>(gout + (size_t)cell * NCELLS_WORDS);
    int4* s = reinterpret_cast<int4*>(g);
    dst[0] = s[0]; dst[1] = s[1]; dst[2] = s[2]; dst[3] = s[3];
}

// ---------------- kernel 2: hot crop+pool using precomputed geometry ----
__global__ __launch_bounds__(128)
void crop_pool_kernel(const float4* __restrict__ bot4,
                      const int* __restrict__ geom,
                      float4* __restrict__ out4, int nwg)
{
    // bijective XCD swizzle (nwg divisible by 8)
    const int bid = blockIdx.x;
    const int blk = (bid & 7) * (nwg >> 3) + (bid >> 3);

    const int* g = geom + (size_t)blk * NCELLS_WORDS;
    const int R0 = rfl(g[0]), R1 = rfl(g[1]), R2 = rfl(g[2]), R3 = rfl(g[3]);
    const int cA = rfl(g[4]), cB = rfl(g[5]), cC = rfl(g[6]), cD = rfl(g[7]);
    const float lx0 = __int_as_float(rfl(g[8]));
    const float lx1 = __int_as_float(rfl(g[9]));
    const float ly0 = __int_as_float(rfl(g[10]));
    const float ly1 = __int_as_float(rfl(g[11]));
    const int msk = rfl(g[12]);

    const int tid = threadIdx.x;                 // one float4 of channels

    float4 X00, X01, X10, X11, X20, X21, X30, X31;
    // Load + x-lerp one row slot with column dedup (SGPR indices ->
    // s_cmp/s_cbranch; skipped loads never issued). Copies are bit-exact.
    auto fresh = [&](int rb, float4& Xs0, float4& Xs1) {
        const float4 a = bot4[rb + cA + tid];
        float4 b; if (cB != cA) b = bot4[rb + cB + tid]; else b = a;
        float4 c; if (cC == cA) c = a; else if (cC == cB) c = b;
                  else c = bot4[rb + cC + tid];
        float4 d; if (cD == cC) d = c; else if (cD == cB) d = b;
                  else d = bot4[rb + cD + tid];
        Xs0 = lerp4(a, b, lx0);
        Xs1 = lerp4(c, d, lx1);
    };

    fresh(R0, X00, X01);
    if (R1 == R0)      { X10 = X00; X11 = X01; }
    else                 fresh(R1, X10, X11);
    if (R2 == R0)      { X20 = X00; X21 = X01; }
    else if (R2 == R1) { X20 = X10; X21 = X11; }
    else                 fresh(R2, X20, X21);
    if (R3 == R2)      { X30 = X20; X31 = X21; }
    else if (R3 == R1) { X30 = X10; X31 = X11; }
    else                 fresh(R3, X30, X31);

    // y-lerp (reference order), mask invalid samples to 0
    const float4 v00 = lerp4(X00, X10, ly0);
    const float4 v01 = lerp4(X01, X11, ly0);
    const float4 v10 = lerp4(X20, X30, ly1);
    const float4 v11 = lerp4(X21, X31, ly1);

    const float4 acc = f4max(
        f4max(mask4(v00, (msk & 1) != 0), mask4(v01, (msk & 2) != 0)),
        f4max(mask4(v10, (msk & 4) != 0), mask4(v11, (msk & 8) != 0)));

    vfloat4 accv; accv.x = acc.x; accv.y = acc.y; accv.z = acc.z; accv.w = acc.w;
    vfloat4* dst = reinterpret_cast<vfloat4*>(
        const_cast<float4*>(&out4[(size_t)blk * C4 + tid]));
    __builtin_nontemporal_store(accv, dst);
}

// ---------------- fallback: monolithic R7 kernel (if ws too small) ------
__global__ __launch_bounds__(128)
void crop_pool_mono(const float4* __restrict__ bot4,
                    const float* __restrict__ rois,
                    const float* __restrict__ im_info,
                    float4* __restrict__ out4, int nwg)
{
    const int bid = blockIdx.x;
    const int blk = (bid & 7) * (nwg >> 3) + (bid >> 3);
    const int n  = blk / (POOLSZ * POOLSZ);
    const int p  = blk - n * (POOLSZ * POOLSZ);
    const int py = p / POOLSZ;
    const int px = p - py * POOLSZ;

    const float inv_w = 1.0f / im_info[1];
    const float inv_h = 1.0f / im_info[0];
    const float* r5 = rois + n * 5;
    const int bb = rfl((int)r5[0]);
    const float rx1 = r5[1] * inv_w, ry1 = r5[2] * inv_h;
    const float rx2 = r5[3] * inv_w, ry2 = r5[4] * inv_h;
    const float sy = (ry2 - ry1) * (float)(Hc - 1) / (float)(CROPSZ - 1);
    const float sx = (rx2 - rx1) * (float)(Wc - 1) / (float)(CROPSZ - 1);
    const float oy = ry1 * (float)(Hc - 1);
    const float ox = rx1 * (float)(Wc - 1);

    int R0, R1, R2, R3; float ly0, ly1; bool vy0, vy1;
    {
        const float ysa = fmaf((float)(2 * py), sy, oy);
        vy0 = (ysa >= 0.f) && (ysa <= (float)(Hc - 1));
        const float fy = floorf(ysa); ly0 = ysa - fy;
        const int y0 = (int)fminf(fmaxf(fy, 0.f), (float)(Hc - 1));
        const int y1 = (int)fminf(fmaxf(ceilf(ysa), 0.f), (float)(Hc - 1));
        R0 = rfl(((bb * Hc + y0) * Wc) * C4);
        R1 = rfl(((bb * Hc + y1) * Wc) * C4);
        const float ysb = fmaf((float)(2 * py + 1), sy, oy);
        vy1 = (ysb >= 0.f) && (ysb <= (float)(Hc - 1));
        const float fy2 = floorf(ysb); ly1 = ysb - fy2;
        const int y2 = (int)fminf(fmaxf(fy2, 0.f), (float)(Hc - 1));
        const int y3 = (int)fminf(fmaxf(ceilf(ysb), 0.f), (float)(Hc - 1));
        R2 = rfl(((bb * Hc + y2) * Wc) * C4);
        R3 = rfl(((bb * Hc + y3) * Wc) * C4);
    }
    int cA, cB, cC, cD; float lx0, lx1; bool vx0, vx1;
    {
        const float xsa = fmaf((float)(2 * px), sx, ox);
        vx0 = (xsa >= 0.f) && (xsa <= (float)(Wc - 1));
        const float fx = floorf(xsa); lx0 = xsa - fx;
        cA = rfl((int)fminf(fmaxf(fx, 0.f), (float)(Wc - 1)) * C4);
        cB = rfl((int)fminf(fmaxf(ceilf(xsa), 0.f), (float)(Wc - 1)) * C4);
        const float xsb = fmaf((float)(2 * px + 1), sx, ox);
        vx1 = (xsb >= 0.f) && (xsb <= (float)(Wc - 1));
        const float fx2 = floorf(xsb); lx1 = xsb - fx2;
        cC = rfl((int)fminf(fmaxf(fx2, 0.f), (float)(Wc - 1)) * C4);
        cD = rfl((int)fminf(fmaxf(ceilf(xsb), 0.f), (float)(Wc - 1)) * C4);
    }
    const int tid = threadIdx.x;
    float4 X00, X01, X10, X11, X20, X21, X30, X31;
    auto fresh = [&](int rb, float4& Xs0, float4& Xs1) {
        const float4 a = bot4[rb + cA + tid];
        float4 b; if (cB != cA) b = bot4[rb + cB + tid]; else b = a;
        float4 c; if (cC == cA) c = a; else if (cC == cB) c = b;
                  else c = bot4[rb + cC + tid];
        float4 d; if (cD == cC) d = c; else if (cD == cB) d = b;
                  else d = bot4[rb + cD + tid];
        Xs0 = lerp4(a, b, lx0);
        Xs1 = lerp4(c, d, lx1);
    };
    fresh(R0, X00, X01);
    if (R1 == R0)      { X10 = X00; X11 = X01; }
    else                 fresh(R1, X10, X11);
    if (R2 == R0)      { X20 = X00; X21 = X01; }
    else if (R2 == R1) { X20 = X10; X21 = X11; }
    else                 fresh(R2, X20, X21);
    if (R3 == R2)      { X30 = X20; X31 = X21; }
    else if (R3 == R1) { X30 = X10; X31 = X11; }
    else                 fresh(R3, X30, X31);
    const float4 v00 = lerp4(X00, X10, ly0);
    const float4 v01 = lerp4(X01, X11, ly0);
    const float4 v10 = lerp4(X20, X30, ly1);
    const float4 v11 = lerp4(X21, X31, ly1);
    const float4 acc = f4max(
        f4max(mask4(v00, vy0 && vx0), mask4(v01, vy0 && vx1)),
        f4max(mask4(v10, vy1 && vx0), mask4(v11, vy1 && vx1)));
    vfloat4 accv; accv.x = acc.x; accv.y = acc.y; accv.z = acc.z; accv.w = acc.w;
    __builtin_nontemporal_store(accv,
        reinterpret_cast<vfloat4*>(&out4[(size_t)blk * C4 + tid]));
}

extern "C" void kernel_launch(void* const* d_in, const int* in_sizes, int n_in,
                              void* d_out, int out_size, void* d_ws, size_t ws_size,
                              hipStream_t stream) {
    const float4* bottom  = (const float4*)d_in[0];
    const float*  rois    = (const float*)d_in[1];
    const float*  im_info = (const float*)d_in[2];
    float4* out = (float4*)d_out;

    const int N = in_sizes[1] / 5;               // 512 ROIs
    const int nwg = N * POOLSZ * POOLSZ;         // 25088, divisible by 8

    const size_t need = (size_t)nwg * NCELLS_WORDS * sizeof(int);  // 1.6 MB
    if (ws_size >= need) {
        int* geom = (int*)d_ws;
        geom_kernel<<<(nwg + 255) / 256, 256, 0, stream>>>(rois, im_info, geom, nwg);
        crop_pool_kernel<<<nwg, 128, 0, stream>>>(bottom, geom, out, nwg);
    } else {
        crop_pool_mono<<<nwg, 128, 0, stream>>>(bottom, rois, im_info, out, nwg);
    }
}

// Round 9
// 29.774 us; speedup vs baseline: 1.1669x; 1.1669x over previous
//
#include <hip/hip_runtime.h>
#include <math.h>

// CropPoolLayer: TF crop_and_resize (bilinear, extrapolation=0) to 14x14
// fused with 2x2 max pool -> [N,7,7,C], NHWC fp32.
// bottom [B=2,H=64,W=64,C=512] fp32, rois [N,5] (bid,x1,y1,x2,y2), im_info[2].
//
// R9 = R7 structure (monolithic per-cell blocks + XCD swizzle + scalarized
// uniform-branch corner dedup + rcp normalize + nt stores) with blocks
// reshaped 128x1 -> 64x2: one wave per cell, each thread owns TWO float4s
// (channel offsets tid and tid+64; second load is same vaddr + offset:1024).
//  - geometry chain computed once per cell (was duplicated in both waves)
//  - per-wave MLP doubles (~14 batched loads) for latency hiding
//  - BW-side identical to R7

constexpr int POOLSZ = 7;
constexpr int CROPSZ = 14;
constexpr int Hc = 64, Wc = 64, C4 = 128;     // C=512 -> 128 float4 lanes

typedef float vfloat4 __attribute__((ext_vector_type(4)));

struct F8 { float4 lo, hi; };                  // 2 float4 per thread

__device__ __forceinline__ float4 lerp4(float4 a, float4 b, float t) {
    return make_float4(fmaf(b.x - a.x, t, a.x),
                       fmaf(b.y - a.y, t, a.y),
                       fmaf(b.z - a.z, t, a.z),
                       fmaf(b.w - a.w, t, a.w));
}
__device__ __forceinline__ F8 lerp8(const F8& a, const F8& b, float t) {
    F8 r; r.lo = lerp4(a.lo, b.lo, t); r.hi = lerp4(a.hi, b.hi, t); return r;
}
__device__ __forceinline__ float4 f4max(float4 a, float4 b) {
    return make_float4(fmaxf(a.x, b.x), fmaxf(a.y, b.y),
                       fmaxf(a.z, b.z), fmaxf(a.w, b.w));
}
__device__ __forceinline__ F8 f8max(const F8& a, const F8& b) {
    F8 r; r.lo = f4max(a.lo, b.lo); r.hi = f4max(a.hi, b.hi); return r;
}
__device__ __forceinline__ F8 mask8(const F8& v, bool ok) {
    F8 r;
    r.lo = ok ? v.lo : make_float4(0.f, 0.f, 0.f, 0.f);
    r.hi = ok ? v.hi : make_float4(0.f, 0.f, 0.f, 0.f);
    return r;
}
__device__ __forceinline__ int rfl(int x) { return __builtin_amdgcn_readfirstlane(x); }

__global__ __launch_bounds__(64)
void crop_pool_kernel(const float4* __restrict__ bot4,
                      const float* __restrict__ rois,
                      const float* __restrict__ im_info,
                      float4* __restrict__ out4, int nwg)
{
    // bijective XCD swizzle (nwg divisible by 8): same-ROI cells share an XCD L2
    const int bid = blockIdx.x;
    const int blk = (bid & 7) * (nwg >> 3) + (bid >> 3);

    const int n  = blk / (POOLSZ * POOLSZ);
    const int p  = blk - n * (POOLSZ * POOLSZ);
    const int py = p / POOLSZ;
    const int px = p - py * POOLSZ;

    const float inv_w = 1.0f / im_info[1];     // im=1024 (pow2) -> exact
    const float inv_h = 1.0f / im_info[0];
    const float* r5 = rois + n * 5;
    const int bb = rfl((int)r5[0]);
    const float rx1 = r5[1] * inv_w, ry1 = r5[2] * inv_h;
    const float rx2 = r5[3] * inv_w, ry2 = r5[4] * inv_h;

    // TF grid: coord = p1*(D-1) + i * ((p2-p1)*(D-1)/(CROP-1))
    const float sy = (ry2 - ry1) * (float)(Hc - 1) / (float)(CROPSZ - 1);
    const float sx = (rx2 - rx1) * (float)(Wc - 1) / (float)(CROPSZ - 1);
    const float oy = ry1 * (float)(Hc - 1);
    const float ox = rx1 * (float)(Wc - 1);

    // ---- y geometry: 4 row slots (premultiplied, scalarized) ----
    int R0, R1, R2, R3;
    float ly0, ly1; bool vy0, vy1;
    {
        const float ysa = fmaf((float)(2 * py), sy, oy);
        vy0 = (ysa >= 0.f) && (ysa <= (float)(Hc - 1));
        const float fy = floorf(ysa); ly0 = ysa - fy;          // unclipped
        const int y0 = (int)fminf(fmaxf(fy, 0.f), (float)(Hc - 1));
        const int y1 = (int)fminf(fmaxf(ceilf(ysa), 0.f), (float)(Hc - 1));
        R0 = rfl(((bb * Hc + y0) * Wc) * C4);
        R1 = rfl(((bb * Hc + y1) * Wc) * C4);
        const float ysb = fmaf((float)(2 * py + 1), sy, oy);
        vy1 = (ysb >= 0.f) && (ysb <= (float)(Hc - 1));
        const float fy2 = floorf(ysb); ly1 = ysb - fy2;
        const int y2 = (int)fminf(fmaxf(fy2, 0.f), (float)(Hc - 1));
        const int y3 = (int)fminf(fmaxf(ceilf(ysb), 0.f), (float)(Hc - 1));
        R2 = rfl(((bb * Hc + y2) * Wc) * C4);
        R3 = rfl(((bb * Hc + y3) * Wc) * C4);
    }
    // ---- x geometry: 4 corner columns (premultiplied, scalarized) ----
    int cA, cB, cC, cD;
    float lx0, lx1; bool vx0, vx1;
    {
        const float xsa = fmaf((float)(2 * px), sx, ox);
        vx0 = (xsa >= 0.f) && (xsa <= (float)(Wc - 1));
        const float fx = floorf(xsa); lx0 = xsa - fx;          // unclipped
        cA = rfl((int)fminf(fmaxf(fx, 0.f), (float)(Wc - 1)) * C4);
        cB = rfl((int)fminf(fmaxf(ceilf(xsa), 0.f), (float)(Wc - 1)) * C4);
        const float xsb = fmaf((float)(2 * px + 1), sx, ox);
        vx1 = (xsb >= 0.f) && (xsb <= (float)(Wc - 1));
        const float fx2 = floorf(xsb); lx1 = xsb - fx2;
        cC = rfl((int)fminf(fmaxf(fx2, 0.f), (float)(Wc - 1)) * C4);
        cD = rfl((int)fminf(fmaxf(ceilf(xsb), 0.f), (float)(Wc - 1)) * C4);
    }

    const int tid = threadIdx.x;                 // two float4s: tid, tid+64

    // X[slot][s]: x-lerped values at row slot, sample column s
    F8 X00, X01, X10, X11, X20, X21, X30, X31;

    // Load + x-lerp one row slot with column dedup. SGPR indices ->
    // s_cmp/s_cbranch uniform branches; skipped loads never issued.
    // Each corner is 2 loads: same base, second at +64 float4s (offset:1024).
    auto fresh = [&](int rb, F8& Xs0, F8& Xs1) {
        F8 a, b, c, d;
        a.lo = bot4[rb + cA + tid]; a.hi = bot4[rb + cA + tid + 64];
        if (cB != cA) { b.lo = bot4[rb + cB + tid]; b.hi = bot4[rb + cB + tid + 64]; }
        else b = a;
        if (cC == cA) c = a; else if (cC == cB) c = b;
        else { c.lo = bot4[rb + cC + tid]; c.hi = bot4[rb + cC + tid + 64]; }
        if (cD == cC) d = c; else if (cD == cB) d = b;
        else { d.lo = bot4[rb + cD + tid]; d.hi = bot4[rb + cD + tid + 64]; }
        Xs0 = lerp8(a, b, lx0);
        Xs1 = lerp8(c, d, lx1);
    };

    fresh(R0, X00, X01);
    if (R1 == R0)      { X10 = X00; X11 = X01; }
    else                 fresh(R1, X10, X11);
    if (R2 == R0)      { X20 = X00; X21 = X01; }
    else if (R2 == R1) { X20 = X10; X21 = X11; }
    else                 fresh(R2, X20, X21);
    if (R3 == R2)      { X30 = X20; X31 = X21; }
    else if (R3 == R1) { X30 = X10; X31 = X11; }
    else                 fresh(R3, X30, X31);

    // y-lerp (reference order: top + (bot-top)*ly), mask invalid samples to 0
    const F8 v00 = lerp8(X00, X10, ly0);
    const F8 v01 = lerp8(X01, X11, ly0);
    const F8 v10 = lerp8(X20, X30, ly1);
    const F8 v11 = lerp8(X21, X31, ly1);

    const F8 acc = f8max(
        f8max(mask8(v00, vy0 && vx0), mask8(v01, vy0 && vx1)),
        f8max(mask8(v10, vy1 && vx0), mask8(v11, vy1 && vx1)));

    // write-once output: nontemporal stores (native vector type for builtin)
    const size_t ob = (size_t)blk * C4 + tid;
    vfloat4 s0; s0.x = acc.lo.x; s0.y = acc.lo.y; s0.z = acc.lo.z; s0.w = acc.lo.w;
    vfloat4 s1; s1.x = acc.hi.x; s1.y = acc.hi.y; s1.z = acc.hi.z; s1.w = acc.hi.w;
    __builtin_nontemporal_store(s0, reinterpret_cast<vfloat4*>(&out4[ob]));
    __builtin_nontemporal_store(s1, reinterpret_cast<vfloat4*>(&out4[ob + 64]));
}

extern "C" void kernel_launch(void* const* d_in, const int* in_sizes, int n_in,
                              void* d_out, int out_size, void* d_ws, size_t ws_size,
                              hipStream_t stream) {
    const float4* bottom  = (const float4*)d_in[0];
    const float*  rois    = (const float*)d_in[1];
    const float*  im_info = (const float*)d_in[2];
    float4* out = (float4*)d_out;

    const int N = in_sizes[1] / 5;               // 512 ROIs
    const int nwg = N * POOLSZ * POOLSZ;         // 25088, divisible by 8

    crop_pool_kernel<<<nwg, 64, 0, stream>>>(bottom, rois, im_info, out, nwg);
}